// Round 12
// baseline (384.404 us; speedup 1.0000x reference)
//
#include <hip/hip_runtime.h>

// CacheFuser on MI355X (gfx950) — round 12.
// r11: occupancy 2x (45.8%) but time flat vs r9 -> limiter is a PER-WAVE
// stall: the 1-deep a-prefetch + per-kt sched_barrier(0x38F) gave each kt's
// L2 W-load only ~40-80cy of lead vs ~200cy L2 latency -> ~150cy vmcnt stall
// every kt, every wave. VGPR_Count=64 says we have ~64 spare regs.
// Single change: 4-slot a-frag ring (3-iteration lead >= L2 latency), drop
// the per-kt sched_barrier (keep only the prologue-ordering one).
// Watchdog: WRITE_SIZE must stay ~131MB (no scheduler-hoist spill).

typedef unsigned int  u32;
typedef unsigned short u16;
typedef __attribute__((ext_vector_type(8))) short bf16x8;   // 8 x bf16
typedef __attribute__((ext_vector_type(4))) float f32x4;

#define LL   8
#define NN   4
#define HH   256
#define RPL  8192            // rows per layer = B*S
#define BM   32              // rows per block

// d_ws layout: per layer 655360 u16; per matrix: k-tile-major 8192-u16 tiles,
// tile kt holds W^T[p][kt*32..kt*32+32) as [p][32] row-major.
#define LSTRIDE 655360
#define O_AKW1 0
#define O_AKW2 65536
#define O_AVW1 131072
#define O_AVW2 196608
#define O_FKW1 262144        // K=512 -> 16 tiles (0..7 recv half, 8..15 agg half)
#define O_FKW2 393216
#define O_FVW1 458752
#define O_FVW2 589824
// total 5242880 u16 = 10485760 B in d_ws

__device__ __forceinline__ u32 f2bf(float f) {
  u32 u = __builtin_bit_cast(u32, f);
  return (u + 0x7fffu + ((u >> 16) & 1u)) >> 16;   // RNE
}
__device__ __forceinline__ float4 ldf4(const float* p) { return *(const float4*)p; }

// ---------------- prep: W[k][p] f32 -> k-tile-major bf16 W^T tiles -----------
__global__ __launch_bounds__(256) void prep_wt_k(
    const float* __restrict__ s0, const float* __restrict__ s1,
    const float* __restrict__ s2, const float* __restrict__ s3,
    const float* __restrict__ s4, const float* __restrict__ s5,
    const float* __restrict__ s6, const float* __restrict__ s7,
    u16* __restrict__ wt)
{
  __shared__ float tile[32][33];
  const int mat = blockIdx.z, l = blockIdx.y, t = blockIdx.x;
  const float* src; int off, K;
  switch (mat) {
    case 0: src = s0; off = O_AKW1; K = 256; break;
    case 1: src = s1; off = O_AKW2; K = 256; break;
    case 2: src = s2; off = O_AVW1; K = 256; break;
    case 3: src = s3; off = O_AVW2; K = 256; break;
    case 4: src = s4; off = O_FKW1; K = 512; break;
    case 5: src = s5; off = O_FKW2; K = 256; break;
    case 6: src = s6; off = O_FVW1; K = 512; break;
    default: src = s7; off = O_FVW2; K = 256; break;
  }
  const int ntk = K >> 5;
  if (t >= ntk * 8) return;                 // 8 p-tiles of 32
  const int tk = t % ntk, tp = t / ntk;
  src += (size_t)l * K * HH;
  u16* dst = wt + (size_t)l * LSTRIDE + off;
  #pragma unroll
  for (int i = 0; i < 4; ++i) {
    int idx = threadIdx.x + i * 256;
    int r = idx >> 5, c = idx & 31;        // r = k-local, c = p-local
    tile[r][c] = src[(size_t)(tk * 32 + r) * HH + tp * 32 + c];
  }
  __syncthreads();
  const int pl = threadIdx.x >> 3, kq = threadIdx.x & 7;
  const int p = tp * 32 + pl;
  ushort4 o;
  o.x = (u16)f2bf(tile[kq * 4 + 0][pl]);
  o.y = (u16)f2bf(tile[kq * 4 + 1][pl]);
  o.z = (u16)f2bf(tile[kq * 4 + 2][pl]);
  o.w = (u16)f2bf(tile[kq * 4 + 3][pl]);
  *(ushort4*)(dst + (size_t)tk * 8192 + p * 32 + kq * 4) = o;
}

// ---------------- main kernel helpers ---------------------------------------
__device__ __forceinline__ void zero22(f32x4 (&a)[2][2]) {
  f32x4 z = {0.f, 0.f, 0.f, 0.f};
  a[0][0] = z; a[0][1] = z; a[1][0] = z; a[1][1] = z;
}

// D[p][q] += W^T[p][k] * Act[q][k] over K=256 (8 k-tiles), no thread barriers.
// Wave w owns p in [w*32, w*32+32): a-frags distinct across waves.
// a-frags: 4-slot ring, prefetch kt+3 during kt (lead ~3 iters >= L2 latency).
// b-frags: swizzled LDS reads from a [32][256] bf16 buffer.
// STG: stream a [32][256] f32 tile (src) into dst as swizzled bf16.
template<bool STG>
__device__ __forceinline__ void gemm8S(
    f32x4 (&acc)[2][2], const u16* __restrict__ wtile, const u16* __restrict__ act,
    const float* __restrict__ src, u16* __restrict__ dst,
    int tid, int w, int lr, int g)
{
  const u16* wl = wtile + (w * 32 + lr) * 32 + g * 8;   // +fp*512, +kt*8192
  bf16x8 a[4][2];
  #pragma unroll
  for (int c = 0; c < 3; ++c)
    #pragma unroll
    for (int fp = 0; fp < 2; ++fp)
      a[c][fp] = *(const bf16x8*)(wl + c * 8192 + fp * 512);
  __builtin_amdgcn_sched_barrier(0x38F);   // pin prologue a-loads ahead of slots
  float4 slot[4];
  if (STG) {
    #pragma unroll
    for (int c = 0; c < 4; ++c)
      slot[c] = ldf4(src + (size_t)(c * 512 + tid) * 4);
  }
  #pragma unroll
  for (int kt = 0; kt < 8; ++kt) {
    const int cur = kt & 3;
    if (kt < 5) {
      #pragma unroll
      for (int fp = 0; fp < 2; ++fp)
        a[(kt + 3) & 3][fp] = *(const bf16x8*)(wl + (kt + 3) * 8192 + fp * 512);
    }
    bf16x8 b[2];
    #pragma unroll
    for (int fq = 0; fq < 2; ++fq) {
      int q = fq * 16 + lr;
      int k = (kt * 32 + g * 8) ^ ((q & 7) << 3);
      b[fq] = *(const bf16x8*)(act + q * HH + k);
    }
    if (STG && (kt & 1)) {
      const int s = kt >> 1;                // 0..3, compile-time after unroll
      int idx = s * 512 + tid;
      int q = idx >> 6, c = (idx & 63) * 4;
      const float4& v = slot[s];
      ushort4 o;
      o.x = (u16)f2bf(v.x); o.y = (u16)f2bf(v.y);
      o.z = (u16)f2bf(v.z); o.w = (u16)f2bf(v.w);
      *(ushort4*)(dst + q * HH + (c ^ ((q & 7) << 3))) = o;
    }
    #pragma unroll
    for (int fp = 0; fp < 2; ++fp)
      #pragma unroll
      for (int fq = 0; fq < 2; ++fq)
        acc[fp][fq] = __builtin_amdgcn_mfma_f32_16x16x32_bf16(a[cur][fp], b[fq], acc[fp][fq], 0, 0, 0);
  }
}

// One-shot staging: [32][256] f32 -> swizzled bf16 LDS.
__device__ __forceinline__ void stageDirect(u16* dst, const float* __restrict__ src, int tid) {
  #pragma unroll
  for (int i = 0; i < 4; ++i) {
    int idx = i * 512 + tid;
    float4 v = ldf4(src + (size_t)idx * 4);
    int q = idx >> 6, c = (idx & 63) * 4;
    ushort4 o;
    o.x = (u16)f2bf(v.x); o.y = (u16)f2bf(v.y);
    o.z = (u16)f2bf(v.z); o.w = (u16)f2bf(v.w);
    *(ushort4*)(dst + q * HH + (c ^ ((q & 7) << 3))) = o;
  }
}

// HF (f32, owner-exclusive RMW): HF[q][p] (+)= sn * relu(acc + b1)
template<bool INIT>
__device__ __forceinline__ void hsUpd(
    float* HF, f32x4 (&acc)[2][2], const float* __restrict__ b1,
    float sn, int w, int lr, int g)
{
  #pragma unroll
  for (int fp = 0; fp < 2; ++fp) {
    int p0 = w * 32 + fp * 16 + g * 4;
    float4 bv = *(const float4*)(b1 + p0);
    #pragma unroll
    for (int fq = 0; fq < 2; ++fq) {
      int q = fq * 16 + lr;
      float* addr = HF + q * HH + (p0 ^ ((q & 7) << 3));
      float4 nv;
      nv.x = sn * fmaxf(acc[fp][fq][0] + bv.x, 0.f);
      nv.y = sn * fmaxf(acc[fp][fq][1] + bv.y, 0.f);
      nv.z = sn * fmaxf(acc[fp][fq][2] + bv.z, 0.f);
      nv.w = sn * fmaxf(acc[fp][fq][3] + bv.w, 0.f);
      if (!INIT) {
        float4 old = *(float4*)addr;
        nv.x += old.x; nv.y += old.y; nv.z += old.z; nv.w += old.w;
      }
      *(float4*)addr = nv;
    }
  }
}

// convert HF (f32 [32][256], swizzled) -> bf16 tile (same swizzle)
__device__ __forceinline__ void convertHS(const float* __restrict__ HF, u16* dst, int tid) {
  #pragma unroll
  for (int j = 0; j < 4; ++j) {
    int idx = j * 512 + tid;
    int q = idx >> 6, c = (idx & 63) * 4;
    int sw = c ^ ((q & 7) << 3);
    float4 v = *(const float4*)(HF + q * HH + sw);
    ushort4 o;
    o.x = (u16)f2bf(v.x); o.y = (u16)f2bf(v.y);
    o.z = (u16)f2bf(v.z); o.w = (u16)f2bf(v.w);
    *(ushort4*)(dst + q * HH + sw) = o;
  }
}

// acc -> swizzled bf16 LDS: v = [relu?](acc + bscale*bias)
__device__ __forceinline__ void epiLds(
    u16* buf, f32x4 (&acc)[2][2], const float* __restrict__ bias,
    float bscale, bool doRelu, int w, int lr, int g)
{
  #pragma unroll
  for (int fp = 0; fp < 2; ++fp) {
    int p0 = w * 32 + fp * 16 + g * 4;
    float4 bv = *(const float4*)(bias + p0);
    #pragma unroll
    for (int fq = 0; fq < 2; ++fq) {
      int q = fq * 16 + lr;
      float v0 = acc[fp][fq][0] + bscale * bv.x;
      float v1 = acc[fp][fq][1] + bscale * bv.y;
      float v2 = acc[fp][fq][2] + bscale * bv.z;
      float v3 = acc[fp][fq][3] + bscale * bv.w;
      if (doRelu) {
        v0 = fmaxf(v0, 0.f); v1 = fmaxf(v1, 0.f);
        v2 = fmaxf(v2, 0.f); v3 = fmaxf(v3, 0.f);
      }
      ushort4 o;
      o.x = (u16)f2bf(v0); o.y = (u16)f2bf(v1);
      o.z = (u16)f2bf(v2); o.w = (u16)f2bf(v3);
      *(ushort4*)(buf + q * HH + (p0 ^ ((q & 7) << 3))) = o;
    }
  }
}

// out = recv + gate*(acc + bias)
__device__ __forceinline__ void epiOut(
    f32x4 (&acc)[2][2], const float* __restrict__ bias,
    const float* __restrict__ recv, float* __restrict__ outp,
    float gate, int w, int lr, int g)
{
  #pragma unroll
  for (int fp = 0; fp < 2; ++fp) {
    int p0 = w * 32 + fp * 16 + g * 4;
    float4 bv = *(const float4*)(bias + p0);
    #pragma unroll
    for (int fq = 0; fq < 2; ++fq) {
      int q = fq * 16 + lr;
      float4 rv = *(const float4*)(recv + (size_t)q * HH + p0);
      float4 ov;
      ov.x = rv.x + gate * (acc[fp][fq][0] + bv.x);
      ov.y = rv.y + gate * (acc[fp][fq][1] + bv.y);
      ov.z = rv.z + gate * (acc[fp][fq][2] + bv.z);
      ov.w = rv.w + gate * (acc[fp][fq][3] + bv.w);
      *(float4*)(outp + (size_t)q * HH + p0) = ov;
    }
  }
}

__global__ __launch_bounds__(512, 4) void CacheFuser_73873437491748_kernel(
    const float* __restrict__ recv_k, const float* __restrict__ recv_v,
    const float* __restrict__ shar_k, const float* __restrict__ shar_v,
    const float* __restrict__ ew, const float* __restrict__ alpha,
    const float* __restrict__ ak_b1, const float* __restrict__ ak_b2,
    const float* __restrict__ av_b1, const float* __restrict__ av_b2,
    const float* __restrict__ fk_b1, const float* __restrict__ fk_b2,
    const float* __restrict__ fv_b1, const float* __restrict__ fv_b2,
    const u16* __restrict__ wt, float* __restrict__ out)
{
  __shared__ u16 XA[BM * HH];    // 16 KB input ping (swizzled bf16)
  __shared__ u16 XB[BM * HH];    // 16 KB input pong
  __shared__ float HF[BM * HH];  // 32 KB f32 hidden-sum; later 2x bf16 scratch
  // total 64 KB -> 2 blocks/CU

  const int bid = blockIdx.x;
  const int l = bid & 7, t = bid >> 3;          // layer <-> XCD affinity
  const int tid = threadIdx.x;
  const int w = tid >> 6, lane = tid & 63, lr = lane & 15, g = lane >> 4;

  u16* F0 = (u16*)HF;            // bf16 scratch 0 (agg tile)
  u16* F1 = (u16*)HF + BM * HH;  // bf16 scratch 1 (fuse-hidden tile)

  const size_t row0 = (size_t)t * BM;
  const u16* lw = wt + (size_t)l * LSTRIDE;
  const float gate = 1.f / (1.f + __expf(-2.f * alpha[l]));
  const float* ewl = ew + l * NN;

  stageDirect(XA, shar_k + ((size_t)l * NN * RPL + row0) * HH, tid);  // K sharer0

  #pragma unroll 1
  for (int path = 0; path < 2; ++path) {
    const float* recvB = (path ? recv_v : recv_k) + ((size_t)l * RPL + row0) * HH;
    const float* sharB = (path ? shar_v : shar_k) + ((size_t)l * NN * RPL + row0) * HH;
    const u16* W1  = lw + (path ? O_AVW1 : O_AKW1);
    const u16* W2  = lw + (path ? O_AVW2 : O_AKW2);
    const u16* FW1 = lw + (path ? O_FVW1 : O_FKW1);
    const u16* FW2 = lw + (path ? O_FVW2 : O_FKW2);
    const float* b1  = (path ? av_b1 : ak_b1) + l * HH;
    const float* b2  = (path ? av_b2 : ak_b2) + l * HH;
    const float* fb1 = (path ? fv_b1 : fk_b1) + l * HH;
    const float* fb2 = (path ? fv_b2 : fk_b2) + l * HH;
    float* outp = out + ((size_t)(path * LL + l) * RPL + row0) * HH;

    int cur = path;
    float sS = 0.f;

    #pragma unroll 1
    for (int n = 0; n < NN; ++n) {
      float sn = ewl[n] * 0.25f; sS += sn;
      __syncthreads();                         // input n ready in cur buffer
      u16* XC = cur ? XB : XA;
      u16* XO = cur ? XA : XB;
      const float* nsrc = (n < 3) ? sharB + (size_t)(n + 1) * RPL * HH : recvB;
      f32x4 h[2][2]; zero22(h);
      gemm8S<true>(h, W1, XC, nsrc, XO, tid, w, lr, g);
      if (n == 0) hsUpd<true >(HF, h, b1, sn, w, lr, g);
      else        hsUpd<false>(HF, h, b1, sn, w, lr, g);
      cur ^= 1;
    }
    // after loop: recv in cur buffer, cur^1 dead (last sharer)
    u16* XR = cur ? XB : XA;
    u16* XD = cur ? XA : XB;
    __syncthreads();                           // HF complete; recv staged
    convertHS(HF, XD, tid);                    // XD = bf16(hsum)
    __syncthreads();
    f32x4 agg[2][2]; zero22(agg);
    gemm8S<false>(agg, W2, XD, nullptr, nullptr, tid, w, lr, g);
    epiLds(F0, agg, b2, sS, false, w, lr, g);  // F0 = agg + sS*b2 (HF now dead)
    __syncthreads();                           // F0 ready; XD reads done
    f32x4 h2[2][2]; zero22(h2);
    if (path == 0) {
      // fuse GEMM1 (recv half) while streaming V-path sharer0 -> XD
      gemm8S<true>(h2, FW1, XR, shar_v + ((size_t)l * NN * RPL + row0) * HH, XD,
                   tid, w, lr, g);
    } else {
      gemm8S<false>(h2, FW1, XR, nullptr, nullptr, tid, w, lr, g);
    }
    gemm8S<false>(h2, FW1 + 8 * 8192, F0, nullptr, nullptr, tid, w, lr, g);  // agg half
    epiLds(F1, h2, fb1, 1.f, true, w, lr, g);  // F1 = fuse hidden (disjoint from F0)
    __syncthreads();                           // F1 ready
    f32x4 dd[2][2]; zero22(dd);
    gemm8S<false>(dd, FW2, F1, nullptr, nullptr, tid, w, lr, g);
    epiOut(dd, fb2, recvB, outp, gate, w, lr, g);
    // path1 input (V sharer0) sits in XD; after cur^=1 the loop reads it.
    cur ^= 1;
  }
}

extern "C" void kernel_launch(void* const* d_in, const int* in_sizes, int n_in,
                              void* d_out, int out_size, void* d_ws, size_t ws_size,
                              hipStream_t stream)
{
  const float* recv_k = (const float*)d_in[0];
  const float* recv_v = (const float*)d_in[1];
  const float* shar_k = (const float*)d_in[2];
  const float* shar_v = (const float*)d_in[3];
  const float* ew     = (const float*)d_in[4];
  const float* alpha  = (const float*)d_in[5];
  const float* ak_w1 = (const float*)d_in[6];  const float* ak_b1 = (const float*)d_in[7];
  const float* ak_w2 = (const float*)d_in[8];  const float* ak_b2 = (const float*)d_in[9];
  const float* av_w1 = (const float*)d_in[10]; const float* av_b1 = (const float*)d_in[11];
  const float* av_w2 = (const float*)d_in[12]; const float* av_b2 = (const float*)d_in[13];
  const float* fk_w1 = (const float*)d_in[14]; const float* fk_b1 = (const float*)d_in[15];
  const float* fk_w2 = (const float*)d_in[16]; const float* fk_b2 = (const float*)d_in[17];
  const float* fv_w1 = (const float*)d_in[18]; const float* fv_b1 = (const float*)d_in[19];
  const float* fv_w2 = (const float*)d_in[20]; const float* fv_b2 = (const float*)d_in[21];
  u16* wtw = (u16*)d_ws;          // 10485760 B
  float* outp = (float*)d_out;

  prep_wt_k<<<dim3(128, 8, 8), dim3(256), 0, stream>>>(
      ak_w1, ak_w2, av_w1, av_w2, fk_w1, fk_w2, fv_w1, fv_w2, wtw);

  CacheFuser_73873437491748_kernel<<<dim3(2048), dim3(512), 0, stream>>>(
      recv_k, recv_v, shar_k, shar_v, ew, alpha,
      ak_b1, ak_b2, av_b1, av_b2, fk_b1, fk_b2, fv_b1, fv_b2, wtw, outp);
}

// Round 13
// 365.273 us; speedup vs baseline: 1.0524x; 1.0524x over previous
//
#include <hip/hip_runtime.h>

// CacheFuser on MI355X (gfx950) — round 13.
// r12's flatline decoded: __launch_bounds__(512,4) = 4 waves/EU budgeted only
// 64 arch regs (VGPR_Count=64) while the 4-deep a-ring pushed demand to ~95
// -> 176MB scratch spill (WRITE 307MB vs 131MB output) ate the prefetch gain.
// Launch-bounds ledger: (512)->128 regs [r5/r6/r9, spill-free <=128 demand];
// (512,2)->128 [r2]; (512,4)->64 [r11/r12].
// Fix: plain __launch_bounds__(512). 128-reg budget + 64KB LDS = 2 blocks/CU
// (16 waves at <=128 regs). Combines the three separately-validated fixes:
// no-spill (r9) + 2 blocks/CU (r11) + 3-iter L2 prefetch lead (r12).
// Everything else byte-identical to r12.

typedef unsigned int  u32;
typedef unsigned short u16;
typedef __attribute__((ext_vector_type(8))) short bf16x8;   // 8 x bf16
typedef __attribute__((ext_vector_type(4))) float f32x4;

#define LL   8
#define NN   4
#define HH   256
#define RPL  8192            // rows per layer = B*S
#define BM   32              // rows per block

// d_ws layout: per layer 655360 u16; per matrix: k-tile-major 8192-u16 tiles,
// tile kt holds W^T[p][kt*32..kt*32+32) as [p][32] row-major.
#define LSTRIDE 655360
#define O_AKW1 0
#define O_AKW2 65536
#define O_AVW1 131072
#define O_AVW2 196608
#define O_FKW1 262144        // K=512 -> 16 tiles (0..7 recv half, 8..15 agg half)
#define O_FKW2 393216
#define O_FVW1 458752
#define O_FVW2 589824
// total 5242880 u16 = 10485760 B in d_ws

__device__ __forceinline__ u32 f2bf(float f) {
  u32 u = __builtin_bit_cast(u32, f);
  return (u + 0x7fffu + ((u >> 16) & 1u)) >> 16;   // RNE
}
__device__ __forceinline__ float4 ldf4(const float* p) { return *(const float4*)p; }

// ---------------- prep: W[k][p] f32 -> k-tile-major bf16 W^T tiles -----------
__global__ __launch_bounds__(256) void prep_wt_k(
    const float* __restrict__ s0, const float* __restrict__ s1,
    const float* __restrict__ s2, const float* __restrict__ s3,
    const float* __restrict__ s4, const float* __restrict__ s5,
    const float* __restrict__ s6, const float* __restrict__ s7,
    u16* __restrict__ wt)
{
  __shared__ float tile[32][33];
  const int mat = blockIdx.z, l = blockIdx.y, t = blockIdx.x;
  const float* src; int off, K;
  switch (mat) {
    case 0: src = s0; off = O_AKW1; K = 256; break;
    case 1: src = s1; off = O_AKW2; K = 256; break;
    case 2: src = s2; off = O_AVW1; K = 256; break;
    case 3: src = s3; off = O_AVW2; K = 256; break;
    case 4: src = s4; off = O_FKW1; K = 512; break;
    case 5: src = s5; off = O_FKW2; K = 256; break;
    case 6: src = s6; off = O_FVW1; K = 512; break;
    default: src = s7; off = O_FVW2; K = 256; break;
  }
  const int ntk = K >> 5;
  if (t >= ntk * 8) return;                 // 8 p-tiles of 32
  const int tk = t % ntk, tp = t / ntk;
  src += (size_t)l * K * HH;
  u16* dst = wt + (size_t)l * LSTRIDE + off;
  #pragma unroll
  for (int i = 0; i < 4; ++i) {
    int idx = threadIdx.x + i * 256;
    int r = idx >> 5, c = idx & 31;        // r = k-local, c = p-local
    tile[r][c] = src[(size_t)(tk * 32 + r) * HH + tp * 32 + c];
  }
  __syncthreads();
  const int pl = threadIdx.x >> 3, kq = threadIdx.x & 7;
  const int p = tp * 32 + pl;
  ushort4 o;
  o.x = (u16)f2bf(tile[kq * 4 + 0][pl]);
  o.y = (u16)f2bf(tile[kq * 4 + 1][pl]);
  o.z = (u16)f2bf(tile[kq * 4 + 2][pl]);
  o.w = (u16)f2bf(tile[kq * 4 + 3][pl]);
  *(ushort4*)(dst + (size_t)tk * 8192 + p * 32 + kq * 4) = o;
}

// ---------------- main kernel helpers ---------------------------------------
__device__ __forceinline__ void zero22(f32x4 (&a)[2][2]) {
  f32x4 z = {0.f, 0.f, 0.f, 0.f};
  a[0][0] = z; a[0][1] = z; a[1][0] = z; a[1][1] = z;
}

// D[p][q] += W^T[p][k] * Act[q][k] over K=256 (8 k-tiles), no thread barriers.
// Wave w owns p in [w*32, w*32+32): a-frags distinct across waves.
// a-frags: 4-slot ring, prefetch kt+3 during kt (lead ~3 iters >= L2 latency).
// b-frags: swizzled LDS reads from a [32][256] bf16 buffer.
// STG: stream a [32][256] f32 tile (src) into dst as swizzled bf16.
template<bool STG>
__device__ __forceinline__ void gemm8S(
    f32x4 (&acc)[2][2], const u16* __restrict__ wtile, const u16* __restrict__ act,
    const float* __restrict__ src, u16* __restrict__ dst,
    int tid, int w, int lr, int g)
{
  const u16* wl = wtile + (w * 32 + lr) * 32 + g * 8;   // +fp*512, +kt*8192
  bf16x8 a[4][2];
  #pragma unroll
  for (int c = 0; c < 3; ++c)
    #pragma unroll
    for (int fp = 0; fp < 2; ++fp)
      a[c][fp] = *(const bf16x8*)(wl + c * 8192 + fp * 512);
  __builtin_amdgcn_sched_barrier(0x38F);   // pin prologue a-loads ahead of slots
  float4 slot[4];
  if (STG) {
    #pragma unroll
    for (int c = 0; c < 4; ++c)
      slot[c] = ldf4(src + (size_t)(c * 512 + tid) * 4);
  }
  #pragma unroll
  for (int kt = 0; kt < 8; ++kt) {
    const int cur = kt & 3;
    if (kt < 5) {
      #pragma unroll
      for (int fp = 0; fp < 2; ++fp)
        a[(kt + 3) & 3][fp] = *(const bf16x8*)(wl + (kt + 3) * 8192 + fp * 512);
    }
    bf16x8 b[2];
    #pragma unroll
    for (int fq = 0; fq < 2; ++fq) {
      int q = fq * 16 + lr;
      int k = (kt * 32 + g * 8) ^ ((q & 7) << 3);
      b[fq] = *(const bf16x8*)(act + q * HH + k);
    }
    if (STG && (kt & 1)) {
      const int s = kt >> 1;                // 0..3, compile-time after unroll
      int idx = s * 512 + tid;
      int q = idx >> 6, c = (idx & 63) * 4;
      const float4& v = slot[s];
      ushort4 o;
      o.x = (u16)f2bf(v.x); o.y = (u16)f2bf(v.y);
      o.z = (u16)f2bf(v.z); o.w = (u16)f2bf(v.w);
      *(ushort4*)(dst + q * HH + (c ^ ((q & 7) << 3))) = o;
    }
    #pragma unroll
    for (int fp = 0; fp < 2; ++fp)
      #pragma unroll
      for (int fq = 0; fq < 2; ++fq)
        acc[fp][fq] = __builtin_amdgcn_mfma_f32_16x16x32_bf16(a[cur][fp], b[fq], acc[fp][fq], 0, 0, 0);
  }
}

// One-shot staging: [32][256] f32 -> swizzled bf16 LDS.
__device__ __forceinline__ void stageDirect(u16* dst, const float* __restrict__ src, int tid) {
  #pragma unroll
  for (int i = 0; i < 4; ++i) {
    int idx = i * 512 + tid;
    float4 v = ldf4(src + (size_t)idx * 4);
    int q = idx >> 6, c = (idx & 63) * 4;
    ushort4 o;
    o.x = (u16)f2bf(v.x); o.y = (u16)f2bf(v.y);
    o.z = (u16)f2bf(v.z); o.w = (u16)f2bf(v.w);
    *(ushort4*)(dst + q * HH + (c ^ ((q & 7) << 3))) = o;
  }
}

// HF (f32, owner-exclusive RMW): HF[q][p] (+)= sn * relu(acc + b1)
template<bool INIT>
__device__ __forceinline__ void hsUpd(
    float* HF, f32x4 (&acc)[2][2], const float* __restrict__ b1,
    float sn, int w, int lr, int g)
{
  #pragma unroll
  for (int fp = 0; fp < 2; ++fp) {
    int p0 = w * 32 + fp * 16 + g * 4;
    float4 bv = *(const float4*)(b1 + p0);
    #pragma unroll
    for (int fq = 0; fq < 2; ++fq) {
      int q = fq * 16 + lr;
      float* addr = HF + q * HH + (p0 ^ ((q & 7) << 3));
      float4 nv;
      nv.x = sn * fmaxf(acc[fp][fq][0] + bv.x, 0.f);
      nv.y = sn * fmaxf(acc[fp][fq][1] + bv.y, 0.f);
      nv.z = sn * fmaxf(acc[fp][fq][2] + bv.z, 0.f);
      nv.w = sn * fmaxf(acc[fp][fq][3] + bv.w, 0.f);
      if (!INIT) {
        float4 old = *(float4*)addr;
        nv.x += old.x; nv.y += old.y; nv.z += old.z; nv.w += old.w;
      }
      *(float4*)addr = nv;
    }
  }
}

// convert HF (f32 [32][256], swizzled) -> bf16 tile (same swizzle)
__device__ __forceinline__ void convertHS(const float* __restrict__ HF, u16* dst, int tid) {
  #pragma unroll
  for (int j = 0; j < 4; ++j) {
    int idx = j * 512 + tid;
    int q = idx >> 6, c = (idx & 63) * 4;
    int sw = c ^ ((q & 7) << 3);
    float4 v = *(const float4*)(HF + q * HH + sw);
    ushort4 o;
    o.x = (u16)f2bf(v.x); o.y = (u16)f2bf(v.y);
    o.z = (u16)f2bf(v.z); o.w = (u16)f2bf(v.w);
    *(ushort4*)(dst + q * HH + sw) = o;
  }
}

// acc -> swizzled bf16 LDS: v = [relu?](acc + bscale*bias)
__device__ __forceinline__ void epiLds(
    u16* buf, f32x4 (&acc)[2][2], const float* __restrict__ bias,
    float bscale, bool doRelu, int w, int lr, int g)
{
  #pragma unroll
  for (int fp = 0; fp < 2; ++fp) {
    int p0 = w * 32 + fp * 16 + g * 4;
    float4 bv = *(const float4*)(bias + p0);
    #pragma unroll
    for (int fq = 0; fq < 2; ++fq) {
      int q = fq * 16 + lr;
      float v0 = acc[fp][fq][0] + bscale * bv.x;
      float v1 = acc[fp][fq][1] + bscale * bv.y;
      float v2 = acc[fp][fq][2] + bscale * bv.z;
      float v3 = acc[fp][fq][3] + bscale * bv.w;
      if (doRelu) {
        v0 = fmaxf(v0, 0.f); v1 = fmaxf(v1, 0.f);
        v2 = fmaxf(v2, 0.f); v3 = fmaxf(v3, 0.f);
      }
      ushort4 o;
      o.x = (u16)f2bf(v0); o.y = (u16)f2bf(v1);
      o.z = (u16)f2bf(v2); o.w = (u16)f2bf(v3);
      *(ushort4*)(buf + q * HH + (p0 ^ ((q & 7) << 3))) = o;
    }
  }
}

// out = recv + gate*(acc + bias)
__device__ __forceinline__ void epiOut(
    f32x4 (&acc)[2][2], const float* __restrict__ bias,
    const float* __restrict__ recv, float* __restrict__ outp,
    float gate, int w, int lr, int g)
{
  #pragma unroll
  for (int fp = 0; fp < 2; ++fp) {
    int p0 = w * 32 + fp * 16 + g * 4;
    float4 bv = *(const float4*)(bias + p0);
    #pragma unroll
    for (int fq = 0; fq < 2; ++fq) {
      int q = fq * 16 + lr;
      float4 rv = *(const float4*)(recv + (size_t)q * HH + p0);
      float4 ov;
      ov.x = rv.x + gate * (acc[fp][fq][0] + bv.x);
      ov.y = rv.y + gate * (acc[fp][fq][1] + bv.y);
      ov.z = rv.z + gate * (acc[fp][fq][2] + bv.z);
      ov.w = rv.w + gate * (acc[fp][fq][3] + bv.w);
      *(float4*)(outp + (size_t)q * HH + p0) = ov;
    }
  }
}

__global__ __launch_bounds__(512) void CacheFuser_73873437491748_kernel(
    const float* __restrict__ recv_k, const float* __restrict__ recv_v,
    const float* __restrict__ shar_k, const float* __restrict__ shar_v,
    const float* __restrict__ ew, const float* __restrict__ alpha,
    const float* __restrict__ ak_b1, const float* __restrict__ ak_b2,
    const float* __restrict__ av_b1, const float* __restrict__ av_b2,
    const float* __restrict__ fk_b1, const float* __restrict__ fk_b2,
    const float* __restrict__ fv_b1, const float* __restrict__ fv_b2,
    const u16* __restrict__ wt, float* __restrict__ out)
{
  __shared__ u16 XA[BM * HH];    // 16 KB input ping (swizzled bf16)
  __shared__ u16 XB[BM * HH];    // 16 KB input pong
  __shared__ float HF[BM * HH];  // 32 KB f32 hidden-sum; later 2x bf16 scratch
  // total 64 KB -> 2 blocks/CU (when VGPR <= 128)

  const int bid = blockIdx.x;
  const int l = bid & 7, t = bid >> 3;          // layer <-> XCD affinity
  const int tid = threadIdx.x;
  const int w = tid >> 6, lane = tid & 63, lr = lane & 15, g = lane >> 4;

  u16* F0 = (u16*)HF;            // bf16 scratch 0 (agg tile)
  u16* F1 = (u16*)HF + BM * HH;  // bf16 scratch 1 (fuse-hidden tile)

  const size_t row0 = (size_t)t * BM;
  const u16* lw = wt + (size_t)l * LSTRIDE;
  const float gate = 1.f / (1.f + __expf(-2.f * alpha[l]));
  const float* ewl = ew + l * NN;

  stageDirect(XA, shar_k + ((size_t)l * NN * RPL + row0) * HH, tid);  // K sharer0

  #pragma unroll 1
  for (int path = 0; path < 2; ++path) {
    const float* recvB = (path ? recv_v : recv_k) + ((size_t)l * RPL + row0) * HH;
    const float* sharB = (path ? shar_v : shar_k) + ((size_t)l * NN * RPL + row0) * HH;
    const u16* W1  = lw + (path ? O_AVW1 : O_AKW1);
    const u16* W2  = lw + (path ? O_AVW2 : O_AKW2);
    const u16* FW1 = lw + (path ? O_FVW1 : O_FKW1);
    const u16* FW2 = lw + (path ? O_FVW2 : O_FKW2);
    const float* b1  = (path ? av_b1 : ak_b1) + l * HH;
    const float* b2  = (path ? av_b2 : ak_b2) + l * HH;
    const float* fb1 = (path ? fv_b1 : fk_b1) + l * HH;
    const float* fb2 = (path ? fv_b2 : fk_b2) + l * HH;
    float* outp = out + ((size_t)(path * LL + l) * RPL + row0) * HH;

    int cur = path;
    float sS = 0.f;

    #pragma unroll 1
    for (int n = 0; n < NN; ++n) {
      float sn = ewl[n] * 0.25f; sS += sn;
      __syncthreads();                         // input n ready in cur buffer
      u16* XC = cur ? XB : XA;
      u16* XO = cur ? XA : XB;
      const float* nsrc = (n < 3) ? sharB + (size_t)(n + 1) * RPL * HH : recvB;
      f32x4 h[2][2]; zero22(h);
      gemm8S<true>(h, W1, XC, nsrc, XO, tid, w, lr, g);
      if (n == 0) hsUpd<true >(HF, h, b1, sn, w, lr, g);
      else        hsUpd<false>(HF, h, b1, sn, w, lr, g);
      cur ^= 1;
    }
    // after loop: recv in cur buffer, cur^1 dead (last sharer)
    u16* XR = cur ? XB : XA;
    u16* XD = cur ? XA : XB;
    __syncthreads();                           // HF complete; recv staged
    convertHS(HF, XD, tid);                    // XD = bf16(hsum)
    __syncthreads();
    f32x4 agg[2][2]; zero22(agg);
    gemm8S<false>(agg, W2, XD, nullptr, nullptr, tid, w, lr, g);
    epiLds(F0, agg, b2, sS, false, w, lr, g);  // F0 = agg + sS*b2 (HF now dead)
    __syncthreads();                           // F0 ready; XD reads done
    f32x4 h2[2][2]; zero22(h2);
    if (path == 0) {
      // fuse GEMM1 (recv half) while streaming V-path sharer0 -> XD
      gemm8S<true>(h2, FW1, XR, shar_v + ((size_t)l * NN * RPL + row0) * HH, XD,
                   tid, w, lr, g);
    } else {
      gemm8S<false>(h2, FW1, XR, nullptr, nullptr, tid, w, lr, g);
    }
    gemm8S<false>(h2, FW1 + 8 * 8192, F0, nullptr, nullptr, tid, w, lr, g);  // agg half
    epiLds(F1, h2, fb1, 1.f, true, w, lr, g);  // F1 = fuse hidden (disjoint from F0)
    __syncthreads();                           // F1 ready
    f32x4 dd[2][2]; zero22(dd);
    gemm8S<false>(dd, FW2, F1, nullptr, nullptr, tid, w, lr, g);
    epiOut(dd, fb2, recvB, outp, gate, w, lr, g);
    // path1 input (V sharer0) sits in XD; after cur^=1 the loop reads it.
    cur ^= 1;
  }
}

extern "C" void kernel_launch(void* const* d_in, const int* in_sizes, int n_in,
                              void* d_out, int out_size, void* d_ws, size_t ws_size,
                              hipStream_t stream)
{
  const float* recv_k = (const float*)d_in[0];
  const float* recv_v = (const float*)d_in[1];
  const float* shar_k = (const float*)d_in[2];
  const float* shar_v = (const float*)d_in[3];
  const float* ew     = (const float*)d_in[4];
  const float* alpha  = (const float*)d_in[5];
  const float* ak_w1 = (const float*)d_in[6];  const float* ak_b1 = (const float*)d_in[7];
  const float* ak_w2 = (const float*)d_in[8];  const float* ak_b2 = (const float*)d_in[9];
  const float* av_w1 = (const float*)d_in[10]; const float* av_b1 = (const float*)d_in[11];
  const float* av_w2 = (const float*)d_in[12]; const float* av_b2 = (const float*)d_in[13];
  const float* fk_w1 = (const float*)d_in[14]; const float* fk_b1 = (const float*)d_in[15];
  const float* fk_w2 = (const float*)d_in[16]; const float* fk_b2 = (const float*)d_in[17];
  const float* fv_w1 = (const float*)d_in[18]; const float* fv_b1 = (const float*)d_in[19];
  const float* fv_w2 = (const float*)d_in[20]; const float* fv_b2 = (const float*)d_in[21];
  u16* wtw = (u16*)d_ws;          // 10485760 B
  float* outp = (float*)d_out;

  prep_wt_k<<<dim3(128, 8, 8), dim3(256), 0, stream>>>(
      ak_w1, ak_w2, av_w1, av_w2, fk_w1, fk_w2, fv_w1, fv_w2, wtw);

  CacheFuser_73873437491748_kernel<<<dim3(2048), dim3(512), 0, stream>>>(
      recv_k, recv_v, shar_k, shar_v, ew, alpha,
      ak_b1, ak_b2, av_b1, av_b2, fk_b1, fk_b2, fv_b1, fv_b2, wtw, outp);
}